// Round 4
// baseline (809.613 us; speedup 1.0000x reference)
//
#include <hip/hip_runtime.h>
#include <hip/hip_fp16.h>

// LSTM: B=256, T=1024, I=64, H=25 (4H=100), O=64. fp32 in/out.
//
// k1 gates_gemm_t: gates_x = x·W_ihᵀ + b_ih + b_hh, stored per-(b,t) row of
//   100 dwords, element (unit r, gate q) at r*4+q  -> one dwordx4 per lane in k2.
//   Transposed through LDS (stride 101, conflict-free) for coalesced stores.
//
// k2 lstm_rec3: 2 batches per wave (128 blocks x 64 thr), ZERO LDS/barriers.
//   lanes 0-31 batch A, 32-63 batch B; lane&31 = hidden unit (25 active).
//   h broadcast per-half via ds_bpermute. FC fused: lane computes outputs
//   (l) and (l+32) of its half's batch. Depth-3 register prefetch of gates.

#define Bn 256
#define Tn 1024
#define In 64
#define Hn 25
#define Gn 100
#define On 64
#define BT (Bn * Tn)
#define ROW 100   // dwords per (b,t) row in gws

__device__ __forceinline__ float frcp(float x) { return __builtin_amdgcn_rcpf(x); }
__device__ __forceinline__ float sigm(float x) { return frcp(1.f + __expf(-x)); }
__device__ __forceinline__ float bperm(int idx_bytes, float v) {
    return __int_as_float(__builtin_amdgcn_ds_bpermute(idx_bytes, __float_as_int(v)));
}

// ---------------- kernel 1: input GEMM -> unit-major-interleaved rows ------
template <typename ST>
__launch_bounds__(256, 2)
__global__ void gates_gemm_t(const float* __restrict__ x,
                             const float* __restrict__ W_ih,
                             const float* __restrict__ b_ih,
                             const float* __restrict__ b_hh,
                             ST* __restrict__ gws) {
    __shared__ float lds[64 * 101];
    const int tid = threadIdx.x;
    const int l   = tid & 63;
    const int q   = __builtin_amdgcn_readfirstlane(tid >> 6);  // gate type 0..3
    const int row = blockIdx.x * 64 + l;                        // b*T + t
    const int g0  = q * Hn;

    const float4* xr = (const float4*)(x + (size_t)row * In);
    float4 xv[16];
#pragma unroll
    for (int c = 0; c < 16; ++c) xv[c] = xr[c];

#pragma unroll
    for (int j = 0; j < Hn; ++j) {
        const int g = g0 + j;
        const float4* wr = (const float4*)(W_ih + (size_t)g * In);  // wave-uniform
        float a0 = 0.f, a1 = 0.f, a2 = 0.f, a3 = 0.f;
#pragma unroll
        for (int c = 0; c < 16; ++c) {
            float4 w = wr[c];
            a0 += w.x * xv[c].x;
            a1 += w.y * xv[c].y;
            a2 += w.z * xv[c].z;
            a3 += w.w * xv[c].w;
        }
        // gate g = (type q, unit j) -> row element j*4 + q
        lds[l * 101 + j * 4 + q] = (a0 + a1) + (a2 + a3) + b_ih[g] + b_hh[g];
    }
    __syncthreads();

    // coalesced writeout: 64 rows x 100 dwords
    ST* gout = gws + (size_t)blockIdx.x * 64 * ROW;
#pragma unroll 1
    for (int idx = tid; idx < 64 * ROW; idx += 256) {
        const int r = idx / ROW;
        const int c = idx - r * ROW;
        gout[idx] = (ST)lds[r * 101 + c];
    }
}

// ---------------- kernel 2: recurrence, 2 batches per wave ----------------
template <typename ST>
struct GateLd;
template <> struct GateLd<float> {
    static __device__ __forceinline__ float4 ld(const float* p) {
        return *(const float4*)p;
    }
};
template <> struct GateLd<__half> {
    static __device__ __forceinline__ float4 ld(const __half* p) {
        ushort4 u = *(const ushort4*)p;
        __half a, b, c, d;
        *(unsigned short*)&a = u.x; *(unsigned short*)&b = u.y;
        *(unsigned short*)&c = u.z; *(unsigned short*)&d = u.w;
        return make_float4((float)a, (float)b, (float)c, (float)d);
    }
};

template <typename ST>
__launch_bounds__(64, 1)
__global__ void lstm_rec3(const ST* __restrict__ gws,
                          const float* __restrict__ W_hh,
                          const float* __restrict__ W_fc,
                          const float* __restrict__ b_fc,
                          float* __restrict__ out) {
    const int lane = threadIdx.x;
    const int half = lane >> 5;            // 0 = batch A, 1 = batch B
    const int m    = lane & 31;            // unit (gates) / output index (FC)
    const int rr   = (m < Hn) ? m : (Hn - 1);
    const int b    = blockIdx.x * 2 + half;

    // per-lane weights
    float wi[Hn], wf[Hn], wg[Hn], wo[Hn], wv0[Hn], wv1[Hn];
#pragma unroll
    for (int j = 0; j < Hn; ++j) {
        wi[j]  = W_hh[(0 * Hn + rr) * Hn + j];
        wf[j]  = W_hh[(1 * Hn + rr) * Hn + j];
        wg[j]  = W_hh[(2 * Hn + rr) * Hn + j];
        wo[j]  = W_hh[(3 * Hn + rr) * Hn + j];
        wv0[j] = W_fc[m * Hn + j];
        wv1[j] = W_fc[(m + 32) * Hn + j];
    }
    const float bf0 = b_fc[m];
    const float bf1 = b_fc[m + 32];

    const ST* gp = gws + (size_t)b * Tn * ROW + rr * 4;
    float* obase = out + (size_t)b * Tn * On + m;

    const int bpbase = (lane & 32) << 2;   // bpermute byte base for own half

    float hb[Hn];
#pragma unroll
    for (int j = 0; j < Hn; ++j) hb[j] = 0.f;
    float c = 0.f;

    float4 q0 = GateLd<ST>::ld(gp + 0 * ROW);
    float4 q1 = GateLd<ST>::ld(gp + 1 * ROW);
    float4 q2 = GateLd<ST>::ld(gp + 2 * ROW);

#pragma unroll 1
    for (int t = 0; t < Tn; ++t) {
        const int tp = (t + 3 < Tn) ? (t + 3) : (Tn - 1);
        float4 nxt = GateLd<ST>::ld(gp + (size_t)tp * ROW);

        // gate pre-activations for step t (4 independent chains)
        float ai = q0.x, af = q0.y, ag = q0.z, ao = q0.w;
#pragma unroll
        for (int j = 0; j < Hn; ++j) {
            ai += wi[j] * hb[j];
            af += wf[j] * hb[j];
            ag += wg[j] * hb[j];
            ao += wo[j] * hb[j];
        }

        // FC output row t-1 from hb (= h_{t-1}); off the critical chain
        if (t > 0) {
            float a0 = bf0, a1 = 0.f, b0 = bf1, b1 = 0.f;
#pragma unroll
            for (int j = 0; j < 24; j += 2) {
                a0 += wv0[j + 0] * hb[j + 0];
                a1 += wv0[j + 1] * hb[j + 1];
                b0 += wv1[j + 0] * hb[j + 0];
                b1 += wv1[j + 1] * hb[j + 1];
            }
            a0 += wv0[24] * hb[24];
            b0 += wv1[24] * hb[24];
            obase[(size_t)(t - 1) * On]      = a0 + a1;
            obase[(size_t)(t - 1) * On + 32] = b0 + b1;
        }

        // activations + cell update (in-lane)
        const float I  = sigm(ai);
        const float F  = sigm(af);
        const float G  = 2.f * sigm(2.f * ag) - 1.f;   // tanh
        const float O_ = sigm(ao);
        c = F * c + I * G;
        const float th = 2.f * sigm(2.f * c) - 1.f;    // tanh(c)
        const float h  = O_ * th;

        // per-half broadcast: hb[j] = h from lane (half*32 + j)
#pragma unroll
        for (int j = 0; j < Hn; ++j) hb[j] = bperm(bpbase + j * 4, h);

        q0 = q1; q1 = q2; q2 = nxt;
    }

    // final FC row (h_{T-1})
    {
        float a0 = bf0, a1 = 0.f, b0 = bf1, b1 = 0.f;
#pragma unroll
        for (int j = 0; j < 24; j += 2) {
            a0 += wv0[j + 0] * hb[j + 0];
            a1 += wv0[j + 1] * hb[j + 1];
            b0 += wv1[j + 0] * hb[j + 0];
            b1 += wv1[j + 1] * hb[j + 1];
        }
        a0 += wv0[24] * hb[24];
        b0 += wv1[24] * hb[24];
        obase[(size_t)(Tn - 1) * On]      = a0 + a1;
        obase[(size_t)(Tn - 1) * On + 32] = b0 + b1;
    }
}

extern "C" void kernel_launch(void* const* d_in, const int* in_sizes, int n_in,
                              void* d_out, int out_size, void* d_ws, size_t ws_size,
                              hipStream_t stream) {
    const float* x    = (const float*)d_in[0];
    const float* W_ih = (const float*)d_in[1];
    const float* W_hh = (const float*)d_in[2];
    const float* b_ih = (const float*)d_in[3];
    const float* b_hh = (const float*)d_in[4];
    const float* W_fc = (const float*)d_in[5];
    const float* b_fc = (const float*)d_in[6];
    float* out = (float*)d_out;

    const size_t need_f32 = (size_t)BT * ROW * sizeof(float);   // 104.9 MB
    const int nb = BT / 64;                                     // 4096 blocks

    if (ws_size >= need_f32) {
        float* gws = (float*)d_ws;
        gates_gemm_t<float><<<nb, 256, 0, stream>>>(x, W_ih, b_ih, b_hh, gws);
        lstm_rec3<float><<<Bn / 2, 64, 0, stream>>>(gws, W_hh, W_fc, b_fc, out);
    } else {
        __half* gws = (__half*)d_ws;
        gates_gemm_t<__half><<<nb, 256, 0, stream>>>(x, W_ih, b_ih, b_hh, gws);
        lstm_rec3<__half><<<Bn / 2, 64, 0, stream>>>(gws, W_hh, W_fc, b_fc, out);
    }
}

// Round 5
// 544.188 us; speedup vs baseline: 1.4877x; 1.4877x over previous
//
#include <hip/hip_runtime.h>
#include <hip/hip_fp16.h>

// LSTM: B=256, T=1024, I=64, H=25 (4H=100), O=64. fp32 in/out.
//
// k1 gates_mfma: gates_x = x·W_ihᵀ + b_ih + b_hh via bf16 MFMA 16x16x32.
//   Output rows gws[b*T+t][unit*4+gate] (100 fp32) so k2 reads ONE dwordx4.
//   Per block: 64 rows (M) × 112 cols (N, 100 live) × K=64. Bias in C-init.
// k2 lstm_rec4: 1 wave per batch (256 blocks), ZERO LDS/barriers.
//   Lane r<25 owns unit r (loads its 4 gate pre-acts as one float4, computes
//   4×25 dots vs h in SGPRs via v_readlane broadcast, cell update in-lane).
//   All 64 lanes do the fused FC for h_{t-1} between dots and activations
//   (independent work to hide trans latency). Depth-4 register ring prefetch.

#define Bn 256
#define Tn 1024
#define In 64
#define Hn 25
#define Gn 100
#define On 64
#define BT (Bn * Tn)
#define ROW 100

typedef __attribute__((ext_vector_type(8))) short short8;
typedef __attribute__((ext_vector_type(4))) float f32x4;

__device__ __forceinline__ float frcp(float x) { return __builtin_amdgcn_rcpf(x); }
__device__ __forceinline__ float sigm(float x) { return frcp(1.f + __expf(-x)); }
__device__ __forceinline__ float bcast(float v, int lane) {
    return __int_as_float(__builtin_amdgcn_readlane(__float_as_int(v), lane));
}
__device__ __forceinline__ short f2bf(float f) {   // RNE fp32 -> bf16 bits
    unsigned u = __float_as_uint(f);
    unsigned r = (u + 0x7FFFu + ((u >> 16) & 1u)) >> 16;
    return (short)r;
}

// ---------------- kernel 1: input GEMM via MFMA ----------------
template <typename ST>
__global__ __launch_bounds__(256, 2)
void gates_mfma(const float* __restrict__ x, const float* __restrict__ W_ih,
                const float* __restrict__ b_ih, const float* __restrict__ b_hh,
                ST* __restrict__ gws) {
    __shared__ short lA[64 * 72];    // x tile, bf16, rows padded to 72 (2-way ok)
    __shared__ short lB[112 * 72];   // permuted W_ih, bf16
    __shared__ float lbias[112];

    const int tid = threadIdx.x;
    const size_t row0 = (size_t)blockIdx.x * 64;

    // stage A: 64 rows of x (fp32 -> bf16), coalesced
    for (int i = tid; i < 64 * 64; i += 256) {
        const int r = i >> 6, k = i & 63;
        lA[r * 72 + k] = f2bf(x[(row0 + r) * In + k]);
    }
    // stage B: B[n][k] = W_ih[gate_row(n)][k], n = unit*4 + gate
    for (int i = tid; i < 112 * 64; i += 256) {
        const int n = i >> 6, k = i & 63;
        float v = 0.f;
        if (n < Gn) {
            const int r = n >> 2, q = n & 3;
            v = W_ih[(size_t)(q * Hn + r) * In + k];
        }
        lB[n * 72 + k] = f2bf(v);
    }
    if (tid < 112) {
        float v = 0.f;
        if (tid < Gn) {
            const int r = tid >> 2, q = tid & 3;
            const int g = q * Hn + r;
            v = b_ih[g] + b_hh[g];
        }
        lbias[tid] = v;
    }
    __syncthreads();

    const int wave = tid >> 6;
    const int lane = tid & 63;
    const int quad = lane >> 4;
    const int l16  = lane & 15;
    const int arow = wave * 16 + l16;   // A fragment row

    // A frags: k in [0,32) and [32,64); A[m=l16][k=quad*8+j]
    const short8 a0 = *(const short8*)&lA[arow * 72 + 0  + quad * 8];
    const short8 a1 = *(const short8*)&lA[arow * 72 + 32 + quad * 8];

#pragma unroll
    for (int nt = 0; nt < 7; ++nt) {
        const int col = nt * 16 + l16;
        const short8 b0 = *(const short8*)&lB[col * 72 + 0  + quad * 8];
        const short8 b1 = *(const short8*)&lB[col * 72 + 32 + quad * 8];
        const float bias = lbias[col];
        f32x4 acc = {bias, bias, bias, bias};
        acc = __builtin_amdgcn_mfma_f32_16x16x32_bf16(a0, b0, acc, 0, 0, 0);
        acc = __builtin_amdgcn_mfma_f32_16x16x32_bf16(a1, b1, acc, 0, 0, 0);
        if (col < Gn) {
#pragma unroll
            for (int i = 0; i < 4; ++i) {
                const size_t grow = row0 + wave * 16 + quad * 4 + i; // C row
                gws[grow * ROW + col] = (ST)acc[i];
            }
        }
    }
}

// ---------------- kernel 2: recurrence, 1 wave / batch ----------------
template <typename ST> struct GateLd;
template <> struct GateLd<float> {
    static __device__ __forceinline__ float4 ld(const float* p) {
        return *(const float4*)p;
    }
};
template <> struct GateLd<__half> {
    static __device__ __forceinline__ float4 ld(const __half* p) {
        ushort4 u = *(const ushort4*)p;
        __half a, b, c, d;
        *(unsigned short*)&a = u.x; *(unsigned short*)&b = u.y;
        *(unsigned short*)&c = u.z; *(unsigned short*)&d = u.w;
        return make_float4((float)a, (float)b, (float)c, (float)d);
    }
};

template <typename ST>
__global__ __launch_bounds__(64, 1)
void lstm_rec4(const ST* __restrict__ gws, const float* __restrict__ W_hh,
               const float* __restrict__ W_fc, const float* __restrict__ b_fc,
               float* __restrict__ out) {
    const int lane = threadIdx.x;
    const int rr   = (lane < Hn) ? lane : (Hn - 1);
    const int b    = blockIdx.x;

    float wi[Hn], wf[Hn], wg[Hn], wo[Hn], wv[Hn];
#pragma unroll
    for (int j = 0; j < Hn; ++j) {
        wi[j] = W_hh[(size_t)(0 * Hn + rr) * Hn + j];
        wf[j] = W_hh[(size_t)(1 * Hn + rr) * Hn + j];
        wg[j] = W_hh[(size_t)(2 * Hn + rr) * Hn + j];
        wo[j] = W_hh[(size_t)(3 * Hn + rr) * Hn + j];
        wv[j] = W_fc[(size_t)lane * Hn + j];
    }
    const float bf = b_fc[lane];

    const ST* gp = gws + ((size_t)b * Tn) * ROW + rr * 4;
    float*    ob = out + ((size_t)b * Tn) * On + lane;

    float hb[Hn];
#pragma unroll
    for (int j = 0; j < Hn; ++j) hb[j] = 0.f;
    float c = 0.f;

    float4 ring[4];
#pragma unroll
    for (int s = 0; s < 4; ++s) ring[s] = GateLd<ST>::ld(gp + (size_t)s * ROW);

#pragma unroll 1
    for (int t0 = 0; t0 < Tn; t0 += 4) {
#pragma unroll
        for (int s = 0; s < 4; ++s) {
            const int t = t0 + s;
            float ai = ring[s].x, af = ring[s].y, ag = ring[s].z, ao = ring[s].w;
#pragma unroll
            for (int j = 0; j < Hn; ++j) {
                ai += wi[j] * hb[j];
                af += wf[j] * hb[j];
                ag += wg[j] * hb[j];
                ao += wo[j] * hb[j];
            }
            // FC output for t-1 (hb still = h_{t-1}); independent of act chain
            if (t > 0) {
                float a0 = bf, a1 = 0.f;
#pragma unroll
                for (int j = 0; j < 24; j += 2) {
                    a0 += wv[j + 0] * hb[j + 0];
                    a1 += wv[j + 1] * hb[j + 1];
                }
                a0 += wv[24] * hb[24];
                ob[(size_t)(t - 1) * On] = a0 + a1;
            }
            // ring prefetch t+4 (clamped, branchless)
            {
                int tp = t + 4; if (tp > Tn - 1) tp = Tn - 1;
                ring[s] = GateLd<ST>::ld(gp + (size_t)tp * ROW);
            }
            // activations + cell update (in-lane)
            const float I  = sigm(ai);
            const float F  = sigm(af);
            const float G  = 2.f * sigm(2.f * ag) - 1.f;   // tanh
            const float O_ = sigm(ao);
            c = F * c + I * G;
            const float th = 2.f * sigm(2.f * c) - 1.f;    // tanh(c)
            const float h  = O_ * th;
            // broadcast h -> SGPR-held hb
#pragma unroll
            for (int j = 0; j < Hn; ++j) hb[j] = bcast(h, j);
        }
    }

    // final FC row (h_{T-1})
    {
        float a0 = bf, a1 = 0.f;
#pragma unroll
        for (int j = 0; j < 24; j += 2) {
            a0 += wv[j + 0] * hb[j + 0];
            a1 += wv[j + 1] * hb[j + 1];
        }
        a0 += wv[24] * hb[24];
        ob[(size_t)(Tn - 1) * On] = a0 + a1;
    }
}

extern "C" void kernel_launch(void* const* d_in, const int* in_sizes, int n_in,
                              void* d_out, int out_size, void* d_ws, size_t ws_size,
                              hipStream_t stream) {
    const float* x    = (const float*)d_in[0];
    const float* W_ih = (const float*)d_in[1];
    const float* W_hh = (const float*)d_in[2];
    const float* b_ih = (const float*)d_in[3];
    const float* b_hh = (const float*)d_in[4];
    const float* W_fc = (const float*)d_in[5];
    const float* b_fc = (const float*)d_in[6];
    float* out = (float*)d_out;

    const size_t need_f32 = (size_t)BT * ROW * sizeof(float);   // 104.9 MB
    const int nb1 = BT / 64;                                    // 4096 blocks

    if (ws_size >= need_f32) {
        float* gws = (float*)d_ws;
        gates_mfma<float><<<nb1, 256, 0, stream>>>(x, W_ih, b_ih, b_hh, gws);
        lstm_rec4<float><<<Bn, 64, 0, stream>>>(gws, W_hh, W_fc, b_fc, out);
    } else {
        __half* gws = (__half*)d_ws;
        gates_mfma<__half><<<nb1, 256, 0, stream>>>(x, W_ih, b_ih, b_hh, gws);
        lstm_rec4<__half><<<Bn, 64, 0, stream>>>(gws, W_hh, W_fc, b_fc, out);
    }
}

// Round 6
// 521.000 us; speedup vs baseline: 1.5540x; 1.0445x over previous
//
#include <hip/hip_runtime.h>
#include <hip/hip_fp16.h>

// LSTM: B=256, T=1024, I=64, H=25 (4H=100), O=64. fp32 in/out.
//
// k1 gates_mfma: gates_x = x·W_ihᵀ + b via bf16 MFMA 16x16x32.
//   gws[b*T+t][unit*4+gate] so k2 reads ONE dwordx4 per step.
// k2 lstm_rec5: 1 wave/batch, zero LDS/barriers. Lane r<25 owns unit r.
//   Packed-f32 dots (f32x2 -> v_pk_fma_f32), h broadcast via v_readlane.
//   FC REMOVED from the loop: h_t overwrites the (already consumed) first
//   25 floats of gws row t  -> no extra workspace.
// k3 fc_gemm: out[bt][:] = h[bt][:]·W_fcᵀ + b_fc, LDS-staged, mem-bound.

#define Bn 256
#define Tn 1024
#define In 64
#define Hn 25
#define Gn 100
#define On 64
#define BT (Bn * Tn)
#define ROW 100

typedef __attribute__((ext_vector_type(8))) short short8;
typedef __attribute__((ext_vector_type(4))) float f32x4;
typedef __attribute__((ext_vector_type(2))) float f32x2;

__device__ __forceinline__ float frcp(float x) { return __builtin_amdgcn_rcpf(x); }
__device__ __forceinline__ float sigm(float x) { return frcp(1.f + __expf(-x)); }
__device__ __forceinline__ float bcast(float v, int lane) {
    return __int_as_float(__builtin_amdgcn_readlane(__float_as_int(v), lane));
}
__device__ __forceinline__ short f2bf(float f) {   // RNE fp32 -> bf16 bits
    unsigned u = __float_as_uint(f);
    unsigned r = (u + 0x7FFFu + ((u >> 16) & 1u)) >> 16;
    return (short)r;
}

// ---------------- kernel 1: input GEMM via MFMA ----------------
template <typename ST>
__global__ __launch_bounds__(256, 4)
void gates_mfma(const float* __restrict__ x, const float* __restrict__ W_ih,
                const float* __restrict__ b_ih, const float* __restrict__ b_hh,
                ST* __restrict__ gws) {
    __shared__ short lA[64 * 72];
    __shared__ short lB[112 * 72];
    __shared__ float lbias[112];

    const int tid = threadIdx.x;
    const size_t row0 = (size_t)blockIdx.x * 64;

    for (int i = tid; i < 64 * 64; i += 256) {
        const int r = i >> 6, k = i & 63;
        lA[r * 72 + k] = f2bf(x[(row0 + r) * In + k]);
    }
    for (int i = tid; i < 112 * 64; i += 256) {
        const int n = i >> 6, k = i & 63;
        float v = 0.f;
        if (n < Gn) {
            const int r = n >> 2, q = n & 3;
            v = W_ih[(size_t)(q * Hn + r) * In + k];
        }
        lB[n * 72 + k] = f2bf(v);
    }
    if (tid < 112) {
        float v = 0.f;
        if (tid < Gn) {
            const int r = tid >> 2, q = tid & 3;
            const int g = q * Hn + r;
            v = b_ih[g] + b_hh[g];
        }
        lbias[tid] = v;
    }
    __syncthreads();

    const int wave = tid >> 6;
    const int lane = tid & 63;
    const int quad = lane >> 4;
    const int l16  = lane & 15;
    const int arow = wave * 16 + l16;

    const short8 a0 = *(const short8*)&lA[arow * 72 + 0  + quad * 8];
    const short8 a1 = *(const short8*)&lA[arow * 72 + 32 + quad * 8];

#pragma unroll
    for (int nt = 0; nt < 7; ++nt) {
        const int col = nt * 16 + l16;
        const short8 b0 = *(const short8*)&lB[col * 72 + 0  + quad * 8];
        const short8 b1 = *(const short8*)&lB[col * 72 + 32 + quad * 8];
        const float bias = lbias[col];
        f32x4 acc = {bias, bias, bias, bias};
        acc = __builtin_amdgcn_mfma_f32_16x16x32_bf16(a0, b0, acc, 0, 0, 0);
        acc = __builtin_amdgcn_mfma_f32_16x16x32_bf16(a1, b1, acc, 0, 0, 0);
        if (col < Gn) {
#pragma unroll
            for (int i = 0; i < 4; ++i) {
                const size_t grow = row0 + wave * 16 + quad * 4 + i;
                gws[grow * ROW + col] = (ST)acc[i];
            }
        }
    }
}

// ---------------- kernel 2: recurrence, 1 wave / batch ----------------
template <typename ST> struct GateLd;
template <> struct GateLd<float> {
    static __device__ __forceinline__ float4 ld(const float* p) {
        return *(const float4*)p;
    }
};
template <> struct GateLd<__half> {
    static __device__ __forceinline__ float4 ld(const __half* p) {
        ushort4 u = *(const ushort4*)p;
        __half a, b, c, d;
        *(unsigned short*)&a = u.x; *(unsigned short*)&b = u.y;
        *(unsigned short*)&c = u.z; *(unsigned short*)&d = u.w;
        return make_float4((float)a, (float)b, (float)c, (float)d);
    }
};

__device__ __forceinline__ float dot25(const f32x2* w, const f32x2* hv, float init) {
    f32x2 a0 = {init, 0.f};
    f32x2 a1 = {0.f, 0.f};
#pragma unroll
    for (int j = 0; j < 13; j += 2) a0 += w[j] * hv[j];   // 7 pk ops
#pragma unroll
    for (int j = 1; j < 13; j += 2) a1 += w[j] * hv[j];   // 6 pk ops
    f32x2 s = a0 + a1;
    return s.x + s.y;
}

template <typename ST>
__global__ __launch_bounds__(64, 1)
void lstm_rec5(ST* __restrict__ gws, const float* __restrict__ W_hh) {
    const int lane = threadIdx.x;
    const int rr   = (lane < Hn) ? lane : (Hn - 1);
    const int b    = blockIdx.x;

    // packed gate weights, 13 f32x2 each (26th element = 0 pad)
    f32x2 wi[13], wf[13], wg[13], wo[13];
#pragma unroll
    for (int j = 0; j < 13; ++j) {
        const int j0 = 2 * j, j1 = 2 * j + 1;
        wi[j].x = W_hh[(size_t)(0 * Hn + rr) * Hn + j0];
        wi[j].y = (j1 < Hn) ? W_hh[(size_t)(0 * Hn + rr) * Hn + j1] : 0.f;
        wf[j].x = W_hh[(size_t)(1 * Hn + rr) * Hn + j0];
        wf[j].y = (j1 < Hn) ? W_hh[(size_t)(1 * Hn + rr) * Hn + j1] : 0.f;
        wg[j].x = W_hh[(size_t)(2 * Hn + rr) * Hn + j0];
        wg[j].y = (j1 < Hn) ? W_hh[(size_t)(2 * Hn + rr) * Hn + j1] : 0.f;
        wo[j].x = W_hh[(size_t)(3 * Hn + rr) * Hn + j0];
        wo[j].y = (j1 < Hn) ? W_hh[(size_t)(3 * Hn + rr) * Hn + j1] : 0.f;
    }

    const ST* gp = gws + ((size_t)b * Tn) * ROW + rr * 4;   // gate loads
    ST*       hw = gws + ((size_t)b * Tn) * ROW + lane;     // h stores (lane<25)

    f32x2 hv[13];
#pragma unroll
    for (int j = 0; j < 13; ++j) hv[j] = (f32x2){0.f, 0.f};
    float c = 0.f;

    float4 ring[4];
#pragma unroll
    for (int s = 0; s < 4; ++s) ring[s] = GateLd<ST>::ld(gp + (size_t)s * ROW);

#pragma unroll 1
    for (int t0 = 0; t0 < Tn; t0 += 4) {
#pragma unroll
        for (int s = 0; s < 4; ++s) {
            const int t = t0 + s;

            const float ai = dot25(wi, hv, ring[s].x);
            const float af = dot25(wf, hv, ring[s].y);
            const float ag = dot25(wg, hv, ring[s].z);
            const float ao = dot25(wo, hv, ring[s].w);

            // ring prefetch t+4 (independent, fills chain shadow)
            {
                int tp = t + 4; if (tp > Tn - 1) tp = Tn - 1;
                ring[s] = GateLd<ST>::ld(gp + (size_t)tp * ROW);
            }

            const float I  = sigm(ai);
            const float F  = sigm(af);
            const float G  = 2.f * sigm(2.f * ag) - 1.f;   // tanh
            const float O_ = sigm(ao);
            c = F * c + I * G;
            const float th = 2.f * sigm(2.f * c) - 1.f;    // tanh(c)
            const float h  = O_ * th;

            // store h_t into the consumed gws row t (offsets 0..24)
            if (lane < Hn) hw[(size_t)t * ROW] = (ST)h;

            // broadcast h -> packed hv (readlanes produce uniform SGPRs)
#pragma unroll
            for (int j = 0; j < 13; ++j) {
                f32x2 v;
                v.x = bcast(h, 2 * j);
                v.y = (2 * j + 1 < Hn) ? bcast(h, 2 * j + 1) : 0.f;
                hv[j] = v;
            }
        }
    }
}

// ---------------- kernel 3: fused FC, memory-bound ----------------
template <typename ST>
__global__ __launch_bounds__(256, 4)
void fc_gemm(const ST* __restrict__ gws, const float* __restrict__ W_fc,
             const float* __restrict__ b_fc, float* __restrict__ out) {
    __shared__ float lw[On * Hn];   // 64 x 25
    __shared__ float lb[On];
    __shared__ float lh[16 * Hn];   // 16 rows of h

    const int tid = threadIdx.x;
    const size_t row0 = (size_t)blockIdx.x * 16;

    for (int i = tid; i < On * Hn; i += 256) lw[i] = W_fc[i];
    if (tid < On) lb[tid] = b_fc[tid];
    for (int i = tid; i < 16 * Hn; i += 256) {
        const int r = i / Hn, j = i - r * Hn;
        lh[i] = (float)gws[(row0 + r) * ROW + j];
    }
    __syncthreads();

#pragma unroll
    for (int it = 0; it < 4; ++it) {
        const int idx = it * 256 + tid;
        const int r = idx >> 6, o = idx & 63;
        float a0 = lb[o], a1 = 0.f;
#pragma unroll
        for (int j = 0; j < 24; j += 2) {
            a0 += lw[o * Hn + j + 0] * lh[r * Hn + j + 0];
            a1 += lw[o * Hn + j + 1] * lh[r * Hn + j + 1];
        }
        a0 += lw[o * Hn + 24] * lh[r * Hn + 24];
        out[(row0 + r) * On + o] = a0 + a1;
    }
}

extern "C" void kernel_launch(void* const* d_in, const int* in_sizes, int n_in,
                              void* d_out, int out_size, void* d_ws, size_t ws_size,
                              hipStream_t stream) {
    const float* x    = (const float*)d_in[0];
    const float* W_ih = (const float*)d_in[1];
    const float* W_hh = (const float*)d_in[2];
    const float* b_ih = (const float*)d_in[3];
    const float* b_hh = (const float*)d_in[4];
    const float* W_fc = (const float*)d_in[5];
    const float* b_fc = (const float*)d_in[6];
    float* out = (float*)d_out;

    const size_t need_f32 = (size_t)BT * ROW * sizeof(float);   // 104.9 MB
    const int nb1 = BT / 64;                                    // 4096
    const int nb3 = BT / 16;                                    // 16384

    if (ws_size >= need_f32) {
        float* gws = (float*)d_ws;
        gates_mfma<float><<<nb1, 256, 0, stream>>>(x, W_ih, b_ih, b_hh, gws);
        lstm_rec5<float><<<Bn, 64, 0, stream>>>(gws, W_hh);
        fc_gemm<float><<<nb3, 256, 0, stream>>>(gws, W_fc, b_fc, out);
    } else {
        __half* gws = (__half*)d_ws;
        gates_mfma<__half><<<nb1, 256, 0, stream>>>(x, W_ih, b_ih, b_hh, gws);
        lstm_rec5<__half><<<Bn, 64, 0, stream>>>(gws, W_hh);
        fc_gemm<__half><<<nb3, 256, 0, stream>>>(gws, W_fc, b_fc, out);
    }
}